// Round 4
// baseline (546.342 us; speedup 1.0000x reference)
//
#include <hip/hip_runtime.h>
#include <hip/hip_bf16.h>

#define NN   512
#define DOBJ 256
#define DBOX 128
#define DIN  640
#define HID  256
#define DOUT 256

typedef __attribute__((ext_vector_type(8))) short  short8;  // bf16x8 MFMA frag
typedef __attribute__((ext_vector_type(4))) float  f32x4;

// workspace layout (float offsets)
#define OFF_A    0u        // A[i,k]  = W1a*obj_i + b1      [512,256]
#define OFF_B    131072u   // B[j,k]  = W1b*obj_j           [512,256]
#define OFF_CA   262144u   // Ca[i,k] = C1a*obj_i + cb1    [512,256]
#define OFF_CB   393216u   // Cb[j,k] = C1b*obj_j          [512,256]
#define OFF_WSV  524288u   // ws[k] = w2*gamma*rsqrt(var+eps) [256]
#define OFF_S    524544u   // s[i] = sum_j conf             [512]
#define OFF_CONF 525312u   // conf                          [512,512]
#define OFF_G    787456u   // G[i,k]                        [512,256]
#define OFF_WSWZ 918528u   // 2 mats x 32768 ushort (128 KB), swizzled bf16 weights

// ---------------------------------------------------------------- helpers
__device__ __forceinline__ ushort bf16u(float x) {
    __hip_bfloat16 h = __float2bfloat16(x);
    union { __hip_bfloat16 b; ushort u; } c; c.b = h;
    return c.u;
}

__device__ __forceinline__ short8 cvt8(float4 a, float4 b) {
    short8 o;
    o[0] = (short)bf16u(a.x); o[1] = (short)bf16u(a.y);
    o[2] = (short)bf16u(a.z); o[3] = (short)bf16u(a.w);
    o[4] = (short)bf16u(b.x); o[5] = (short)bf16u(b.y);
    o[6] = (short)bf16u(b.z); o[7] = (short)bf16u(b.w);
    return o;
}

// ---------------------------------------------------------------- precompute via MFMA
__global__ __launch_bounds__(256, 2) void k_pre_mfma(
    const float* __restrict__ obj, const float* __restrict__ w1,
    const float* __restrict__ cw1, const float* __restrict__ b1,
    const float* __restrict__ cb1,
    float* __restrict__ A, float* __restrict__ B,
    float* __restrict__ Ca, float* __restrict__ Cb)
{
    const int bx = blockIdx.x;            // 0:A 1:B 2:Ca 3:Cb
    const int i0 = blockIdx.y * 64;
    const int tid = threadIdx.x;
    const int w = tid >> 6, lane = tid & 63;
    const int lr = lane & 15, lg = lane >> 4;

    const float* src = (bx & 2) ? cw1 : w1;
    const int dof = (bx & 1) * DOBJ;

    f32x4 acc[4][4];
#pragma unroll
    for (int a = 0; a < 4; ++a)
#pragma unroll
        for (int b = 0; b < 4; ++b) acc[a][b] = (f32x4){0.f, 0.f, 0.f, 0.f};

#pragma unroll
    for (int ks = 0; ks < 8; ++ks) {
        short8 af[4], bf[4];
#pragma unroll
        for (int ms = 0; ms < 4; ++ms) {
            const float* ap = obj + (size_t)(i0 + ms * 16 + lr) * DOBJ + ks * 32 + lg * 8;
            af[ms] = cvt8(*(const float4*)ap, *(const float4*)(ap + 4));
        }
#pragma unroll
        for (int t = 0; t < 4; ++t) {
            const int kc = w * 64 + t * 16 + lr;
            const float* bp = src + (size_t)kc * DIN + dof + ks * 32 + lg * 8;
            bf[t] = cvt8(*(const float4*)bp, *(const float4*)(bp + 4));
        }
#pragma unroll
        for (int ms = 0; ms < 4; ++ms)
#pragma unroll
            for (int t = 0; t < 4; ++t)
                acc[ms][t] = __builtin_amdgcn_mfma_f32_16x16x32_bf16(
                    af[ms], bf[t], acc[ms][t], 0, 0, 0);
    }

    float* dst = (bx == 0) ? A : (bx == 1) ? B : (bx == 2) ? Ca : Cb;
    const float* bias = (bx == 0) ? b1 : (bx == 2) ? cb1 : nullptr;
    float bb[4];
#pragma unroll
    for (int t = 0; t < 4; ++t)
        bb[t] = bias ? bias[w * 64 + t * 16 + lr] : 0.f;

#pragma unroll
    for (int ms = 0; ms < 4; ++ms)
#pragma unroll
        for (int t = 0; t < 4; ++t)
#pragma unroll
            for (int r = 0; r < 4; ++r) {
                const int i = i0 + ms * 16 + lg * 4 + r;
                const int kc = w * 64 + t * 16 + lr;
                dst[(size_t)i * HID + kc] = acc[ms][t][r] + bb[t];
            }
}

__global__ void k_wsvec(const float* __restrict__ w2, const float* __restrict__ gamma,
                        const float* __restrict__ var, float* __restrict__ wsv)
{
    const int k = threadIdx.x;
    wsv[k] = w2[k] * gamma[k] * rsqrtf(var[k] + 1e-5f);
}

// bf16 swizzled weight image: idx = k*128 + ((d>>3 ^ (k&7))<<3) + (d&7)
__global__ __launch_bounds__(128) void k_wprep(
    const float* __restrict__ w1, const float* __restrict__ cw1,
    ushort* __restrict__ wswz)
{
    const int k = blockIdx.x, mat = blockIdx.y, d = threadIdx.x;
    const float* src = mat ? cw1 : w1;
    const float v = src[(size_t)k * DIN + 2 * DOBJ + d];
    const int c = d >> 3;
    const int idx = k * 128 + (((c ^ (k & 7)) << 3)) + (d & 7);
    wswz[(size_t)mat * 32768 + idx] = bf16u(v);
}

// ---------------------------------------------------------------- fused conf + softmax
// block = row i (512 thr, 8 waves = 2 jw x 4 kw). Weights staged ONCE, reused
// over all 512 j. Per-iteration-disjoint red[] -> single barrier before softmax.
__global__ __launch_bounds__(512, 4) void k_conf_fused(
    const float* __restrict__ bbox, const ushort* __restrict__ wswz,
    const float* __restrict__ A_, const float* __restrict__ B_,
    const float* __restrict__ wsv, const float* __restrict__ mask,
    float* __restrict__ conf, float* __restrict__ s_out)
{
    const int i = blockIdx.x;
    const int tid = threadIdx.x;
    const int wv = tid >> 6, lane = tid & 63;
    const int jw = wv >> 2, kw = wv & 3;
    const int lr = lane & 15, lg = lane >> 4;

    __shared__ ushort wlds[32768];       // 64 KB swizzled w1c
    __shared__ float  red[4][512];       // [kw][j] partials, disjoint per iter
    __shared__ float  wred[3][8];

    {
        const uint4* g = (const uint4*)wswz;
        uint4* l = (uint4*)wlds;
#pragma unroll
        for (int n = 0; n < 8; ++n) l[n * 512 + tid] = g[n * 512 + tid];
    }
    __syncthreads();

    float as_t[4], ws_t[4];
#pragma unroll
    for (int t = 0; t < 4; ++t) {
        const int kk = kw * 64 + t * 16 + lr;
        as_t[t] = A_[(size_t)i * HID + kk];
        ws_t[t] = wsv[kk];
    }

    for (int it = 0; it < 4; ++it) {
        const int j0 = it * 128 + jw * 64;

        f32x4 acc[4][4];
#pragma unroll
        for (int a = 0; a < 4; ++a)
#pragma unroll
            for (int b = 0; b < 4; ++b) acc[a][b] = (f32x4){0.f, 0.f, 0.f, 0.f};

#pragma unroll
        for (int ks = 0; ks < 4; ++ks) {
            short8 bf[4];
#pragma unroll
            for (int t = 0; t < 4; ++t) {
                const int kk = kw * 64 + t * 16 + lr;
                const int c  = (ks * 4 + lg) ^ (lr & 7);
                bf[t] = *(const short8*)&wlds[kk * 128 + (c << 3)];
            }
#pragma unroll
            for (int ms = 0; ms < 4; ++ms) {
                const float* ap = bbox +
                    (((size_t)i * NN + j0 + ms * 16 + lr) * DBOX + ks * 32 + lg * 8);
                const short8 af = cvt8(*(const float4*)ap, *(const float4*)(ap + 4));
#pragma unroll
                for (int t = 0; t < 4; ++t)
                    acc[ms][t] = __builtin_amdgcn_mfma_f32_16x16x32_bf16(
                        af, bf[t], acc[ms][t], 0, 0, 0);
            }
        }

#pragma unroll
        for (int ms = 0; ms < 4; ++ms)
#pragma unroll
            for (int r = 0; r < 4; ++r) {
                const int j = j0 + ms * 16 + lg * 4 + r;
                const float* Bj = B_ + (size_t)j * HID + kw * 64 + lr;
                float pj = 0.f;
#pragma unroll
                for (int t = 0; t < 4; ++t) {
                    float h = acc[ms][t][r] + as_t[t] + Bj[t * 16];
                    h = fmaxf(h, 0.01f * h);           // LeakyReLU
                    pj = fmaf(h, ws_t[t], pj);
                }
                pj += __shfl_xor(pj, 1);  pj += __shfl_xor(pj, 2);
                pj += __shfl_xor(pj, 4);  pj += __shfl_xor(pj, 8);
                if (lr == 0) red[kw][j] = pj;
            }
    }
    __syncthreads();

    // in-block softmax + mask + renorm over j = tid
    const float r0 = red[0][tid] + red[1][tid] + red[2][tid] + red[3][tid];
    const float mk = mask[(size_t)i * NN + tid];

    float m = r0;
#pragma unroll
    for (int off = 32; off; off >>= 1) m = fmaxf(m, __shfl_xor(m, off));
    if (lane == 0) wred[0][wv] = m;
    __syncthreads();
    float M = wred[0][0];
#pragma unroll
    for (int u = 1; u < 8; ++u) M = fmaxf(M, wred[0][u]);

    const float e = __expf(r0 - M);
    float sa = e, sk = e * mk;
#pragma unroll
    for (int off = 32; off; off >>= 1) {
        sa += __shfl_xor(sa, off);
        sk += __shfl_xor(sk, off);
    }
    if (lane == 0) { wred[1][wv] = sa; wred[2][wv] = sk; }
    __syncthreads();
    float SA = 0.f, SK = 0.f;
#pragma unroll
    for (int u = 0; u < 8; ++u) { SA += wred[1][u]; SK += wred[2][u]; }
    const float dinv = 1.f / (SK + 1e-8f * SA);

    conf[(size_t)i * NN + tid] = e * mk * dinv;
    if (tid == 0) s_out[i] = SK * dinv;
}

// ---------------------------------------------------------------- fused gacc
// block = row i. G[i,k] = sum_j conf[i,j]*relu(P + Ca[i,k] + Cb[j,k]); no atomics.
__global__ __launch_bounds__(512, 4) void k_gacc_fused(
    const float* __restrict__ bbox, const ushort* __restrict__ wswz,
    const float* __restrict__ Ca_, const float* __restrict__ Cb_,
    const float* __restrict__ conf, float* __restrict__ G)
{
    const int i = blockIdx.x;
    const int tid = threadIdx.x;
    const int wv = tid >> 6, lane = tid & 63;
    const int jw = wv >> 2, kw = wv & 3;
    const int lr = lane & 15, lg = lane >> 4;

    __shared__ ushort wlds[32768];       // 64 KB swizzled cw1c
    __shared__ float  conf_s[512];
    __shared__ float  gred[2][256];

    {
        const uint4* g = (const uint4*)wswz;
        uint4* l = (uint4*)wlds;
#pragma unroll
        for (int n = 0; n < 8; ++n) l[n * 512 + tid] = g[n * 512 + tid];
    }
    conf_s[tid] = conf[(size_t)i * NN + tid];
    __syncthreads();

    float as_t[4];
#pragma unroll
    for (int t = 0; t < 4; ++t)
        as_t[t] = Ca_[(size_t)i * HID + kw * 64 + t * 16 + lr];

    float gk[4] = {0.f, 0.f, 0.f, 0.f};

    for (int it = 0; it < 4; ++it) {
        const int j0 = it * 128 + jw * 64;

        f32x4 acc[4][4];
#pragma unroll
        for (int a = 0; a < 4; ++a)
#pragma unroll
            for (int b = 0; b < 4; ++b) acc[a][b] = (f32x4){0.f, 0.f, 0.f, 0.f};

#pragma unroll
        for (int ks = 0; ks < 4; ++ks) {
            short8 bf[4];
#pragma unroll
            for (int t = 0; t < 4; ++t) {
                const int kk = kw * 64 + t * 16 + lr;
                const int c  = (ks * 4 + lg) ^ (lr & 7);
                bf[t] = *(const short8*)&wlds[kk * 128 + (c << 3)];
            }
#pragma unroll
            for (int ms = 0; ms < 4; ++ms) {
                const float* ap = bbox +
                    (((size_t)i * NN + j0 + ms * 16 + lr) * DBOX + ks * 32 + lg * 8);
                const short8 af = cvt8(*(const float4*)ap, *(const float4*)(ap + 4));
#pragma unroll
                for (int t = 0; t < 4; ++t)
                    acc[ms][t] = __builtin_amdgcn_mfma_f32_16x16x32_bf16(
                        af, bf[t], acc[ms][t], 0, 0, 0);
            }
        }

#pragma unroll
        for (int ms = 0; ms < 4; ++ms)
#pragma unroll
            for (int r = 0; r < 4; ++r) {
                const int j = j0 + ms * 16 + lg * 4 + r;
                const float cf = conf_s[j];
                const float* Bj = Cb_ + (size_t)j * HID + kw * 64 + lr;
#pragma unroll
                for (int t = 0; t < 4; ++t) {
                    float h = acc[ms][t][r] + as_t[t] + Bj[t * 16];
                    gk[t] = fmaf(cf, fmaxf(h, 0.f), gk[t]);
                }
            }
    }

#pragma unroll
    for (int t = 0; t < 4; ++t) {
        float v = gk[t];
        v += __shfl_xor(v, 16);
        v += __shfl_xor(v, 32);
        if (lg == 0) gred[jw][kw * 64 + t * 16 + lr] = v;
    }
    __syncthreads();
    if (tid < 256) G[(size_t)i * DOUT + tid] = gred[0][tid] + gred[1][tid];
}

// ---------------------------------------------------------------- final small GEMM
__global__ __launch_bounds__(256) void k_out(
    const float* __restrict__ G, const float* __restrict__ cw2,
    const float* __restrict__ cb2, const float* __restrict__ s_in,
    float* __restrict__ out)
{
    const int i = blockIdx.x, o = threadIdx.x;
    __shared__ float Gs[DOUT];
    Gs[o] = G[(size_t)i * DOUT + o];
    __syncthreads();
    const float* wr = cw2 + (size_t)o * HID;
    float acc = 0.f;
#pragma unroll 4
    for (int k = 0; k < HID; ++k) acc = fmaf(Gs[k], wr[k], acc);
    out[(size_t)i * DOUT + o] = acc + s_in[i] * cb2[o];
}

// ---------------------------------------------------------------- launch
extern "C" void kernel_launch(void* const* d_in, const int* in_sizes, int n_in,
                              void* d_out, int out_size, void* d_ws, size_t ws_size,
                              hipStream_t stream)
{
    const float* obj  = (const float*)d_in[0];
    const float* bbox = (const float*)d_in[1];
    const float* mask = (const float*)d_in[2];
    const float* w1   = (const float*)d_in[3];
    const float* b1   = (const float*)d_in[4];
    const float* bn_g = (const float*)d_in[5];
    const float* bn_v = (const float*)d_in[8];
    const float* w2   = (const float*)d_in[9];
    const float* cw1  = (const float*)d_in[11];
    const float* cb1  = (const float*)d_in[12];
    const float* cw2  = (const float*)d_in[13];
    const float* cb2  = (const float*)d_in[14];

    float* ws   = (float*)d_ws;
    float* A    = ws + OFF_A;
    float* B    = ws + OFF_B;
    float* Ca   = ws + OFF_CA;
    float* Cb   = ws + OFF_CB;
    float* wsv  = ws + OFF_WSV;
    float* sbuf = ws + OFF_S;
    float* conf = ws + OFF_CONF;
    float* G    = ws + OFF_G;
    ushort* wswz = (ushort*)(ws + OFF_WSWZ);
    float* out  = (float*)d_out;

    k_pre_mfma<<<dim3(4, 8), 256, 0, stream>>>(obj, w1, cw1, b1, cb1, A, B, Ca, Cb);
    k_wsvec<<<1, 256, 0, stream>>>(w2, bn_g, bn_v, wsv);
    k_wprep<<<dim3(256, 2), 128, 0, stream>>>(w1, cw1, wswz);
    k_conf_fused<<<NN, 512, 0, stream>>>(bbox, wswz, A, B, wsv, mask, conf, sbuf);
    k_gacc_fused<<<NN, 512, 0, stream>>>(bbox, wswz + 32768, Ca, Cb, conf, G);
    k_out<<<NN, 256, 0, stream>>>(G, cw2, cb2, sbuf, out);
}

// Round 5
// 407.986 us; speedup vs baseline: 1.3391x; 1.3391x over previous
//
#include <hip/hip_runtime.h>
#include <hip/hip_bf16.h>

#define NN   512
#define DOBJ 256
#define DBOX 128
#define DIN  640
#define HID  256
#define DOUT 256
#define GI   8      // i's per block in pair kernels

typedef __attribute__((ext_vector_type(8))) short  short8;  // bf16x8 MFMA frag
typedef __attribute__((ext_vector_type(4))) float  f32x4;

// workspace layout (float offsets)
#define OFF_A    0u        // A[i,k]  = W1a*obj_i + b1      [512,256]
#define OFF_B    131072u   // B[j,k]  = W1b*obj_j           [512,256]
#define OFF_CA   262144u   // Ca[i,k] = C1a*obj_i + cb1    [512,256]
#define OFF_CB   393216u   // Cb[j,k] = C1b*obj_j          [512,256]
#define OFF_S    524544u   // s[i] = sum_j conf             [512]
#define OFF_CONF 525312u   // conf_raw then conf            [512,512]
#define OFF_G    787456u   // G[i,k]                        [512,256]

// ---------------------------------------------------------------- helpers
__device__ __forceinline__ ushort bf16u(float x) {
    __hip_bfloat16 h = __float2bfloat16(x);
    union { __hip_bfloat16 b; ushort u; } c; c.b = h;
    return c.u;
}

__device__ __forceinline__ short8 cvt8(float4 a, float4 b) {
    short8 o;
    o[0] = (short)bf16u(a.x); o[1] = (short)bf16u(a.y);
    o[2] = (short)bf16u(a.z); o[3] = (short)bf16u(a.w);
    o[4] = (short)bf16u(b.x); o[5] = (short)bf16u(b.y);
    o[6] = (short)bf16u(b.z); o[7] = (short)bf16u(b.w);
    return o;
}

// ---------------------------------------------------------------- precompute via MFMA
__global__ __launch_bounds__(256, 2) void k_pre_mfma(
    const float* __restrict__ obj, const float* __restrict__ w1,
    const float* __restrict__ cw1, const float* __restrict__ b1,
    const float* __restrict__ cb1,
    float* __restrict__ A, float* __restrict__ B,
    float* __restrict__ Ca, float* __restrict__ Cb)
{
    const int bx = blockIdx.x;            // 0:A 1:B 2:Ca 3:Cb
    const int i0 = blockIdx.y * 64;
    const int tid = threadIdx.x;
    const int w = tid >> 6, lane = tid & 63;
    const int lr = lane & 15, lg = lane >> 4;

    const float* src = (bx & 2) ? cw1 : w1;
    const int dof = (bx & 1) * DOBJ;

    f32x4 acc[4][4];
#pragma unroll
    for (int a = 0; a < 4; ++a)
#pragma unroll
        for (int b = 0; b < 4; ++b) acc[a][b] = (f32x4){0.f, 0.f, 0.f, 0.f};

#pragma unroll
    for (int ks = 0; ks < 8; ++ks) {
        short8 af[4], bf[4];
#pragma unroll
        for (int ms = 0; ms < 4; ++ms) {
            const float* ap = obj + (size_t)(i0 + ms * 16 + lr) * DOBJ + ks * 32 + lg * 8;
            af[ms] = cvt8(*(const float4*)ap, *(const float4*)(ap + 4));
        }
#pragma unroll
        for (int t = 0; t < 4; ++t) {
            const int kc = w * 64 + t * 16 + lr;
            const float* bp = src + (size_t)kc * DIN + dof + ks * 32 + lg * 8;
            bf[t] = cvt8(*(const float4*)bp, *(const float4*)(bp + 4));
        }
#pragma unroll
        for (int ms = 0; ms < 4; ++ms)
#pragma unroll
            for (int t = 0; t < 4; ++t)
                acc[ms][t] = __builtin_amdgcn_mfma_f32_16x16x32_bf16(
                    af[ms], bf[t], acc[ms][t], 0, 0, 0);
    }

    float* dst = (bx == 0) ? A : (bx == 1) ? B : (bx == 2) ? Ca : Cb;
    const float* bias = (bx == 0) ? b1 : (bx == 2) ? cb1 : nullptr;
    float bb[4];
#pragma unroll
    for (int t = 0; t < 4; ++t)
        bb[t] = bias ? bias[w * 64 + t * 16 + lr] : 0.f;

#pragma unroll
    for (int ms = 0; ms < 4; ++ms)
#pragma unroll
        for (int t = 0; t < 4; ++t)
#pragma unroll
            for (int r = 0; r < 4; ++r) {
                const int i = i0 + ms * 16 + lg * 4 + r;
                const int kc = w * 64 + t * 16 + lr;
                dst[(size_t)i * HID + kc] = acc[ms][t][r] + bb[t];
            }
}

// ---------------------------------------------------------------- conf (register-resident weights, i-loop)
// block = (j-tile of 64, 8 i's); 256 thr, 4 waves; wave w owns k-cols [w*64,w*64+64).
// Weight frags in VGPRs, loaded once. Main loop: bbox loads + cvt + MFMA only.
__global__ __launch_bounds__(256, 2) void k_conf(
    const float* __restrict__ bbox, const float* __restrict__ w1,
    const float* __restrict__ A_, const float* __restrict__ B_,
    const float* __restrict__ w2, const float* __restrict__ bn_g,
    const float* __restrict__ bn_v, float* __restrict__ conf_raw)
{
    const int j0 = blockIdx.x * 64;
    const int i0 = blockIdx.y * GI;
    const int tid = threadIdx.x;
    const int w = tid >> 6, lane = tid & 63;
    const int lr = lane & 15, lg = lane >> 4;

    __shared__ float red[2][4][64];

    // weight fragments: once per block, directly from fp32 w1 (L2-resident)
    short8 bf[4][4];
    float ws_t[4];
#pragma unroll
    for (int t = 0; t < 4; ++t) {
        const int kk = w * 64 + t * 16 + lr;
        ws_t[t] = w2[kk] * bn_g[kk] * rsqrtf(bn_v[kk] + 1e-5f);
#pragma unroll
        for (int ks = 0; ks < 4; ++ks) {
            const float* bp = w1 + (size_t)kk * DIN + 2 * DOBJ + ks * 32 + lg * 8;
            bf[t][ks] = cvt8(*(const float4*)bp, *(const float4*)(bp + 4));
        }
    }

    for (int g = 0; g < GI; ++g) {
        const int i = i0 + g;
        const int p = g & 1;

        float as_t[4];
#pragma unroll
        for (int t = 0; t < 4; ++t)
            as_t[t] = A_[(size_t)i * HID + w * 64 + t * 16 + lr];

        f32x4 acc[4][4];
#pragma unroll
        for (int a = 0; a < 4; ++a)
#pragma unroll
            for (int b = 0; b < 4; ++b) acc[a][b] = (f32x4){0.f, 0.f, 0.f, 0.f};

#pragma unroll
        for (int ks = 0; ks < 4; ++ks)
#pragma unroll
            for (int ms = 0; ms < 4; ++ms) {
                const float* ap = bbox +
                    (((size_t)i * NN + j0 + ms * 16 + lr) * DBOX + ks * 32 + lg * 8);
                const short8 af = cvt8(*(const float4*)ap, *(const float4*)(ap + 4));
#pragma unroll
                for (int t = 0; t < 4; ++t)
                    acc[ms][t] = __builtin_amdgcn_mfma_f32_16x16x32_bf16(
                        af, bf[t][ks], acc[ms][t], 0, 0, 0);
            }

#pragma unroll
        for (int ms = 0; ms < 4; ++ms)
#pragma unroll
            for (int r = 0; r < 4; ++r) {
                const int j = j0 + ms * 16 + lg * 4 + r;
                const float* Bj = B_ + (size_t)j * HID + w * 64 + lr;
                float pj = 0.f;
#pragma unroll
                for (int t = 0; t < 4; ++t) {
                    float h = acc[ms][t][r] + as_t[t] + Bj[t * 16];
                    h = fmaxf(h, 0.01f * h);           // LeakyReLU
                    pj = fmaf(h, ws_t[t], pj);
                }
                pj += __shfl_xor(pj, 1);  pj += __shfl_xor(pj, 2);
                pj += __shfl_xor(pj, 4);  pj += __shfl_xor(pj, 8);
                if (lr == 0) red[p][w][ms * 16 + lg * 4 + r] = pj;
            }
        __syncthreads();
        if (tid < 64)
            conf_raw[(size_t)i * NN + j0 + tid] =
                red[p][0][tid] + red[p][1][tid] + red[p][2][tid] + red[p][3][tid];
        // no second barrier: next iteration writes red[p^1]; reuse of red[p]
        // happens only after the NEXT barrier, by which readers are done.
    }
}

// ---------------------------------------------------------------- row softmax + zero G
__global__ __launch_bounds__(256) void k_softmax(
    const float* __restrict__ conf_raw, const float* __restrict__ mask,
    float* __restrict__ conf, float* __restrict__ s_out, float* __restrict__ G)
{
    const int i = blockIdx.x, tid = threadIdx.x;
    const int lane = tid & 63, w = tid >> 6;
    __shared__ float wred[3][4];

    G[(size_t)i * DOUT + tid] = 0.f;     // replaces memset launch

    const float r0 = conf_raw[(size_t)i * NN + tid];
    const float r1 = conf_raw[(size_t)i * NN + 256 + tid];
    const float mk0 = mask[(size_t)i * NN + tid];
    const float mk1 = mask[(size_t)i * NN + 256 + tid];

    float m = fmaxf(r0, r1);
#pragma unroll
    for (int off = 32; off; off >>= 1) m = fmaxf(m, __shfl_down(m, off));
    if (lane == 0) wred[0][w] = m;
    __syncthreads();
    const float M = fmaxf(fmaxf(wred[0][0], wred[0][1]), fmaxf(wred[0][2], wred[0][3]));

    const float e0 = __expf(r0 - M), e1 = __expf(r1 - M);
    float sa = e0 + e1;
    float sk = e0 * mk0 + e1 * mk1;
#pragma unroll
    for (int off = 32; off; off >>= 1) {
        sa += __shfl_down(sa, off);
        sk += __shfl_down(sk, off);
    }
    if (lane == 0) { wred[1][w] = sa; wred[2][w] = sk; }
    __syncthreads();
    const float SA = wred[1][0] + wred[1][1] + wred[1][2] + wred[1][3];
    const float SK = wred[2][0] + wred[2][1] + wred[2][2] + wred[2][3];
    const float dinv = 1.f / (SK + 1e-8f * SA);

    conf[(size_t)i * NN + tid]       = e0 * mk0 * dinv;
    conf[(size_t)i * NN + 256 + tid] = e1 * mk1 * dinv;
    if (tid == 0) s_out[i] = SK * dinv;
}

// ---------------------------------------------------------------- gacc (register weights, i-loop, no barriers)
__global__ __launch_bounds__(256, 2) void k_gacc(
    const float* __restrict__ bbox, const float* __restrict__ cw1,
    const float* __restrict__ Ca_, const float* __restrict__ Cb_,
    const float* __restrict__ conf, float* __restrict__ G)
{
    const int j0 = blockIdx.x * 64;
    const int i0 = blockIdx.y * GI;
    const int tid = threadIdx.x;
    const int w = tid >> 6, lane = tid & 63;
    const int lr = lane & 15, lg = lane >> 4;

    short8 bf[4][4];
#pragma unroll
    for (int t = 0; t < 4; ++t) {
        const int kk = w * 64 + t * 16 + lr;
#pragma unroll
        for (int ks = 0; ks < 4; ++ks) {
            const float* bp = cw1 + (size_t)kk * DIN + 2 * DOBJ + ks * 32 + lg * 8;
            bf[t][ks] = cvt8(*(const float4*)bp, *(const float4*)(bp + 4));
        }
    }

    for (int g = 0; g < GI; ++g) {
        const int i = i0 + g;

        float as_t[4];
#pragma unroll
        for (int t = 0; t < 4; ++t)
            as_t[t] = Ca_[(size_t)i * HID + w * 64 + t * 16 + lr];

        f32x4 acc[4][4];
#pragma unroll
        for (int a = 0; a < 4; ++a)
#pragma unroll
            for (int b = 0; b < 4; ++b) acc[a][b] = (f32x4){0.f, 0.f, 0.f, 0.f};

#pragma unroll
        for (int ks = 0; ks < 4; ++ks)
#pragma unroll
            for (int ms = 0; ms < 4; ++ms) {
                const float* ap = bbox +
                    (((size_t)i * NN + j0 + ms * 16 + lr) * DBOX + ks * 32 + lg * 8);
                const short8 af = cvt8(*(const float4*)ap, *(const float4*)(ap + 4));
#pragma unroll
                for (int t = 0; t < 4; ++t)
                    acc[ms][t] = __builtin_amdgcn_mfma_f32_16x16x32_bf16(
                        af, bf[t][ks], acc[ms][t], 0, 0, 0);
            }

        const float* cfrow = conf + (size_t)i * NN + j0;
        float gk[4] = {0.f, 0.f, 0.f, 0.f};
#pragma unroll
        for (int ms = 0; ms < 4; ++ms)
#pragma unroll
            for (int r = 0; r < 4; ++r) {
                const int jL = ms * 16 + lg * 4 + r;
                const float cf = cfrow[jL];
                const float* Bj = Cb_ + (size_t)(j0 + jL) * HID + w * 64 + lr;
#pragma unroll
                for (int t = 0; t < 4; ++t) {
                    float h = acc[ms][t][r] + as_t[t] + Bj[t * 16];
                    gk[t] = fmaf(cf, fmaxf(h, 0.f), gk[t]);
                }
            }
#pragma unroll
        for (int t = 0; t < 4; ++t) {
            float v = gk[t];
            v += __shfl_xor(v, 16);
            v += __shfl_xor(v, 32);
            if (lg == 0)
                atomicAdd(&G[(size_t)i * DOUT + w * 64 + t * 16 + lr], v);
        }
    }
}

// ---------------------------------------------------------------- final small GEMM
__global__ __launch_bounds__(256) void k_out(
    const float* __restrict__ G, const float* __restrict__ cw2,
    const float* __restrict__ cb2, const float* __restrict__ s_in,
    float* __restrict__ out)
{
    const int i = blockIdx.x, o = threadIdx.x;
    __shared__ float Gs[DOUT];
    Gs[o] = G[(size_t)i * DOUT + o];
    __syncthreads();
    const float* wr = cw2 + (size_t)o * HID;
    float acc = 0.f;
#pragma unroll 4
    for (int k = 0; k < HID; ++k) acc = fmaf(Gs[k], wr[k], acc);
    out[(size_t)i * DOUT + o] = acc + s_in[i] * cb2[o];
}

// ---------------------------------------------------------------- launch
extern "C" void kernel_launch(void* const* d_in, const int* in_sizes, int n_in,
                              void* d_out, int out_size, void* d_ws, size_t ws_size,
                              hipStream_t stream)
{
    const float* obj  = (const float*)d_in[0];
    const float* bbox = (const float*)d_in[1];
    const float* mask = (const float*)d_in[2];
    const float* w1   = (const float*)d_in[3];
    const float* b1   = (const float*)d_in[4];
    const float* bn_g = (const float*)d_in[5];
    const float* bn_v = (const float*)d_in[8];
    const float* w2   = (const float*)d_in[9];
    const float* cw1  = (const float*)d_in[11];
    const float* cb1  = (const float*)d_in[12];
    const float* cw2  = (const float*)d_in[13];
    const float* cb2  = (const float*)d_in[14];

    float* ws   = (float*)d_ws;
    float* A    = ws + OFF_A;
    float* B    = ws + OFF_B;
    float* Ca   = ws + OFF_CA;
    float* Cb   = ws + OFF_CB;
    float* sbuf = ws + OFF_S;
    float* conf = ws + OFF_CONF;
    float* G    = ws + OFF_G;
    float* out  = (float*)d_out;

    k_pre_mfma<<<dim3(4, 8), 256, 0, stream>>>(obj, w1, cw1, b1, cb1, A, B, Ca, Cb);
    k_conf<<<dim3(8, NN / GI), 256, 0, stream>>>(bbox, w1, A, B, w2, bn_g, bn_v, conf);
    k_softmax<<<NN, 256, 0, stream>>>(conf, mask, conf, sbuf, G);
    k_gacc<<<dim3(8, NN / GI), 256, 0, stream>>>(bbox, cw1, Ca, Cb, conf, G);
    k_out<<<NN, 256, 0, stream>>>(G, cw2, cb2, sbuf, out);
}